// Round 3
// baseline (49.043 us; speedup 1.0000x reference)
//
#include <hip/hip_runtime.h>

// Problem constants (fixed by setup_inputs): B=8, L=16384, H=2, BLOCK=128, VOCAB=32000
#define NB        8
#define LLEN      16384
#define NHEAD     2
#define BLOCKSZ   128
#define VOCAB     32000
#define NBLK      (LLEN / BLOCKSZ)                  // 128
#define NCHUNK    (NB * NBLK)                       // 1024
#define TOKS_PER_CHUNK (BLOCKSZ * NHEAD)            // 256
#define NT_COLS   (TOKS_PER_CHUNK + LLEN * NHEAD)   // 33024 per batch row
#define NT_TOTAL  (NB * NT_COLS)                    // 264192
#define CAT_TOTAL (NB * TOKS_PER_CHUNK)             // 2048
#define HIST_OFF  (NT_TOTAL + CAT_TOTAL)            // 266240
#define HIST_F4   (NCHUNK * VOCAB / 4)              // 8,192,000 float4s

#define FILL_BLOCKS 2048

typedef float f32x4 __attribute__((ext_vector_type(4)));

// Kernel 1: pure streaming zero of the hist region — fillBuffer-style.
// No LDS, no barriers, no tail: this is 98.5% of all bytes.
__global__ __launch_bounds__(256) void zero_hist(float* __restrict__ hist) {
    const f32x4 z = {0.f, 0.f, 0.f, 0.f};
    f32x4* __restrict__ p = reinterpret_cast<f32x4*>(hist);
    const int stride = FILL_BLOCKS * 256;
    for (size_t i = blockIdx.x * 256 + threadIdx.x; i < HIST_F4; i += stride)
        __builtin_nontemporal_store(z, p + i);
}

// Kernel 2: per-chunk token outputs + sparse histogram counts (rows already zero).
__global__ __launch_bounds__(256) void scatter_kernel(const int* __restrict__ tokens,
                                                      float* __restrict__ out) {
    __shared__ int toks[TOKS_PER_CHUNK];
    const int tid = threadIdx.x;
    const int chunk = blockIdx.x;                 // b*128 + n
    const int b = chunk >> 7;
    const int n = chunk & 127;

    // tokens[b, n*128 .. n*128+127, 0..1] = 256 contiguous ints at chunk*256
    const int v = tokens[(size_t)chunk * TOKS_PER_CHUNK + tid];
    toks[tid] = v;
    const float fv = (float)v;

    // new_tokens flat part (contiguous 256 floats for this chunk)
    out[(size_t)b * NT_COLS + TOKS_PER_CHUNK + n * TOKS_PER_CHUNK + tid] = fv;
    if (tid < NHEAD) {
        // toks[0..1] = tokens[b, n*128, h] -> cat entries
        out[(size_t)b * NT_COLS + n * NHEAD + tid] = fv;                       // new_tokens head
        out[(size_t)NT_TOTAL + b * TOKS_PER_CHUNK + n * NHEAD + tid] = fv;     // cat_ids
    }
    __syncthreads();

    // duplicate scan over the 256 tokens (LDS broadcast reads, conflict-free)
    int c = 0, first = -1;
    #pragma unroll 8
    for (int j = 0; j < TOKS_PER_CHUNK; ++j) {
        const int u = toks[j];
        c += (u == v);
        if (u == v && first < 0) first = j;
    }
    if (first == tid)
        out[(size_t)HIST_OFF + (size_t)chunk * VOCAB + v] = (float)c;
}

extern "C" void kernel_launch(void* const* d_in, const int* in_sizes, int n_in,
                              void* d_out, int out_size, void* d_ws, size_t ws_size,
                              hipStream_t stream) {
    const int* tokens = (const int*)d_in[0];
    float* out = (float*)d_out;

    zero_hist<<<FILL_BLOCKS, 256, 0, stream>>>(out + HIST_OFF);
    scatter_kernel<<<NCHUNK, 256, 0, stream>>>(tokens, out);
}

// Round 4
// 31.636 us; speedup vs baseline: 1.5502x; 1.5502x over previous
//
#include <hip/hip_runtime.h>

// Problem constants (fixed by setup_inputs): B=8, L=16384, H=2, BLOCK=128, VOCAB=32000
#define NB        8
#define LLEN      16384
#define NHEAD     2
#define BLOCKSZ   128
#define VOCAB     32000
#define NBLK      (LLEN / BLOCKSZ)                  // 128
#define NCHUNK    (NB * NBLK)                       // 1024
#define TOKS_PER_CHUNK (BLOCKSZ * NHEAD)            // 256
#define NT_COLS   (TOKS_PER_CHUNK + LLEN * NHEAD)   // 33024 per batch row
#define NT_TOTAL  (NB * NT_COLS)                    // 264192
#define CAT_TOTAL (NB * TOKS_PER_CHUNK)             // 2048
#define HIST_OFF  (NT_TOTAL + CAT_TOTAL)            // 266240
#define NF4       (VOCAB / 4)                       // 8000 float4s per row
#define CAP       16                                // bucket capacity (overflow -> fallback)

typedef float f32x4 __attribute__((ext_vector_type(4)));

// One workgroup per (b,n) chunk. Each thread t "owns" f4 indices g = t + 256k.
// Tokens are bucketed (in LDS) to their owner thread, so the owner writes each
// f4 EXACTLY ONCE (zero or merged counts) — no global-store barrier anywhere.
__global__ __launch_bounds__(256) void fused_kernel(const int* __restrict__ tokens,
                                                    float* __restrict__ out) {
    __shared__ int toks[TOKS_PER_CHUNK];
    __shared__ unsigned bcnt[256];
    __shared__ int bval[256][CAP];
    __shared__ int overflow;

    const int tid = threadIdx.x;
    const int chunk = blockIdx.x;                 // b*128 + n
    const int b = chunk >> 7;
    const int n = chunk & 127;

    const int v = tokens[(size_t)chunk * TOKS_PER_CHUNK + tid];
    toks[tid] = v;
    bcnt[tid] = 0;
    if (tid == 0) overflow = 0;
    __syncthreads();

    // bucket push: owner thread of value v is (v>>2)&255
    {
        const int o = (v >> 2) & 255;
        unsigned slot = atomicAdd(&bcnt[o], 1u);
        if (slot < CAP) bval[o][slot] = v;
        else overflow = 1;                        // racy same-value store, read after barrier
    }
    __syncthreads();                              // LDS-only dependencies

    // token outputs (issued here; never waited on by a barrier afterwards)
    const float fv = (float)v;
    out[(size_t)b * NT_COLS + TOKS_PER_CHUNK + n * TOKS_PER_CHUNK + tid] = fv;
    if (tid < NHEAD) {
        out[(size_t)b * NT_COLS + n * NHEAD + tid] = fv;                    // new_tokens cat part
        out[(size_t)NT_TOTAL + b * TOKS_PER_CHUNK + n * NHEAD + tid] = fv;  // cat_ids
    }

    float* __restrict__ row = out + (size_t)HIST_OFF + (size_t)chunk * VOCAB;
    f32x4* __restrict__ row4 = reinterpret_cast<f32x4*>(row);

    if (!overflow) {
        const int n_e = (int)bcnt[tid];
        unsigned kmask = 0;
        for (int e = 0; e < n_e; ++e)
            kmask |= 1u << (bval[tid][e] >> 10);  // k = v>>10 in [0,31]

        #pragma unroll 4
        for (int k = 0; k < 32; ++k) {
            const int g = tid + (k << 8);
            if (g < NF4) {
                f32x4 f = {0.f, 0.f, 0.f, 0.f};
                if ((kmask >> k) & 1u) {          // rare
                    for (int e = 0; e < n_e; ++e) {
                        const int ve = bval[tid][e];
                        if ((ve >> 10) == k) {
                            int c = 0;
                            for (int e2 = 0; e2 < n_e; ++e2)
                                c += (bval[tid][e2] == ve);
                            f[ve & 3] = (float)c; // dup entries overwrite same value
                        }
                    }
                }
                row4[g] = f;                      // plain store (L2/L3 write-combine)
            }
        }
    } else {
        // Fallback (any-data correctness): zero all, drain, 256-scan, scatter.
        const f32x4 z = {0.f, 0.f, 0.f, 0.f};
        for (int k = 0; k < 32; ++k) {
            const int g = tid + (k << 8);
            if (g < NF4) row4[g] = z;
        }
        __syncthreads();
        int c = 0, first = -1;
        for (int j = 0; j < TOKS_PER_CHUNK; ++j) {
            const int u = toks[j];
            c += (u == v);
            if (u == v && first < 0) first = j;
        }
        if (first == tid) row[v] = (float)c;
    }
}

extern "C" void kernel_launch(void* const* d_in, const int* in_sizes, int n_in,
                              void* d_out, int out_size, void* d_ws, size_t ws_size,
                              hipStream_t stream) {
    const int* tokens = (const int*)d_in[0];
    float* out = (float*)d_out;
    fused_kernel<<<NCHUNK, 256, 0, stream>>>(tokens, out);
}

// Round 5
// 28.422 us; speedup vs baseline: 1.7255x; 1.1130x over previous
//
#include <hip/hip_runtime.h>

// Problem constants (fixed by setup_inputs): B=8, L=16384, H=2, BLOCK=128, VOCAB=32000
#define NB        8
#define LLEN      16384
#define NHEAD     2
#define BLOCKSZ   128
#define VOCAB     32000
#define NBLK      (LLEN / BLOCKSZ)                  // 128
#define NCHUNK    (NB * NBLK)                       // 1024
#define TOKS_PER_CHUNK (BLOCKSZ * NHEAD)            // 256
#define NT_COLS   (TOKS_PER_CHUNK + LLEN * NHEAD)   // 33024 per batch row
#define NT_TOTAL  (NB * NT_COLS)                    // 264192
#define CAT_TOTAL (NB * TOKS_PER_CHUNK)             // 2048
#define HIST_OFF  (NT_TOTAL + CAT_TOTAL)            // 266240
#define NF4       (VOCAB / 4)                       // 8000 float4s per row
#define CAP       16                                // bucket capacity (overflow -> fallback)
#define CAPP      17                                // padded stride (kills LDS bank conflicts)

typedef float f32x4 __attribute__((ext_vector_type(4)));

// One workgroup per (b,n) chunk. Thread t owns f4 indices g = t + 256k.
// Phase A: branch-free zero burst (fill-rate stores). Per-wave vmcnt fence.
// Phase B: same-thread scalar overwrites with duplicate counts (avg 1/thread).
__global__ __launch_bounds__(256) void fused_kernel(const int* __restrict__ tokens,
                                                    float* __restrict__ out) {
    __shared__ int toks[TOKS_PER_CHUNK];
    __shared__ unsigned bcnt[256];
    __shared__ int bval[256][CAPP];
    __shared__ int overflow;

    const int tid = threadIdx.x;
    const int chunk = blockIdx.x;                 // b*128 + n
    const int b = chunk >> 7;
    const int n = chunk & 127;

    const int v = tokens[(size_t)chunk * TOKS_PER_CHUNK + tid];
    bcnt[tid] = 0;
    if (tid == 0) overflow = 0;
    toks[tid] = v;
    __syncthreads();

    // bucket push: owner thread of value v is (v>>2)&255
    {
        const int o = (v >> 2) & 255;
        unsigned slot = atomicAdd(&bcnt[o], 1u);
        if (slot < CAP) bval[o][slot] = v;
        else overflow = 1;                        // racy same-value store, read after barrier
    }
    __syncthreads();

    // token outputs (small, drained together with the burst)
    const float fv = (float)v;
    out[(size_t)b * NT_COLS + TOKS_PER_CHUNK + n * TOKS_PER_CHUNK + tid] = fv;
    if (tid < NHEAD) {
        out[(size_t)b * NT_COLS + n * NHEAD + tid] = fv;                    // new_tokens cat part
        out[(size_t)NT_TOTAL + b * TOKS_PER_CHUNK + n * NHEAD + tid] = fv;  // cat_ids
    }

    float* __restrict__ row = out + (size_t)HIST_OFF + (size_t)chunk * VOCAB;
    f32x4* __restrict__ row4 = reinterpret_cast<f32x4*>(row);

    if (!overflow) {
        // ---- Phase A: pure zero burst, no branches, no LDS deps ----
        const f32x4 z = {0.f, 0.f, 0.f, 0.f};
        #pragma unroll
        for (int k = 0; k < 31; ++k)              // 31*256 = 7936 f4s
            row4[tid + (k << 8)] = z;
        if (tid < 64) row4[7936 + tid] = z;       // tail: 64 f4s by wave 0

        // per-wave fence: my zero stores are retired before my overwrites
        asm volatile("s_waitcnt vmcnt(0)" ::: "memory");

        // ---- Phase B: overwrite my owned slots with counts ----
        const int n_e = (int)bcnt[tid];           // <= CAP here
        for (int e = 0; e < n_e; ++e) {
            const int ve = bval[tid][e];
            int c = 0; bool first = true;
            for (int e2 = 0; e2 < n_e; ++e2) {
                const int u = bval[tid][e2];
                c += (u == ve);
                if (u == ve && e2 < e) first = false;
            }
            if (first) row[ve] = (float)c;        // line is L2-dirty, disjoint bytes
        }
    } else {
        // Fallback (any-data correctness): zero all, block drain, scan, scatter.
        const f32x4 z = {0.f, 0.f, 0.f, 0.f};
        for (int k = 0; k < 32; ++k) {
            const int g = tid + (k << 8);
            if (g < NF4) row4[g] = z;
        }
        __syncthreads();
        int c = 0, first = -1;
        for (int j = 0; j < TOKS_PER_CHUNK; ++j) {
            const int u = toks[j];
            c += (u == v);
            if (u == v && first < 0) first = j;
        }
        if (first == tid) row[v] = (float)c;
    }
}

extern "C" void kernel_launch(void* const* d_in, const int* in_sizes, int n_in,
                              void* d_out, int out_size, void* d_ws, size_t ws_size,
                              hipStream_t stream) {
    const int* tokens = (const int*)d_in[0];
    float* out = (float*)d_out;
    fused_kernel<<<NCHUNK, 256, 0, stream>>>(tokens, out);
}